// Round 4
// baseline (274.725 us; speedup 1.0000x reference)
//
#include <hip/hip_runtime.h>

typedef unsigned short u16;
typedef unsigned int u32;
typedef __attribute__((ext_vector_type(8))) short short8;
typedef __attribute__((ext_vector_type(4))) float f32x4;

#define MFMA16(a, b, c) __builtin_amdgcn_mfma_f32_16x16x32_bf16(a, b, c, 0, 0, 0)

// B=2, S=2048, D=1024, H=16, KVH=4, dk=64, G=4
#define SEQ 2048
#define DM 1024

__device__ __forceinline__ u16 f2bf(float f) {
  u32 u = __float_as_uint(f);
  u += 0x7fffu + ((u >> 16) & 1u);  // RNE
  return (u16)(u >> 16);
}
__device__ __forceinline__ u32 pack2(float a, float b) {  // RNE pack
  return (u32)f2bf(a) | ((u32)f2bf(b) << 16);
}
__device__ __forceinline__ u32 pack2t(float a, float b) {  // truncating pack: 1 v_perm
  return __builtin_amdgcn_perm(__float_as_uint(b), __float_as_uint(a), 0x07060302u);
}

// ---------- fused prep: 3x fp32->bf16 convert + 4x weight transpose ----------
// grid (1024, 7): y<3 converts, y>=3 transposes (x = kt*32 + nt)
__global__ void k_prep(const float* __restrict__ qin, const float* __restrict__ kin,
                       const float* __restrict__ vin, const float* __restrict__ Wq,
                       const float* __restrict__ Wk, const float* __restrict__ Wv,
                       const float* __restrict__ Wo, u16* __restrict__ qo,
                       u16* __restrict__ ko, u16* __restrict__ vo, u16* __restrict__ WqT,
                       u16* __restrict__ WkT, u16* __restrict__ WvT, u16* __restrict__ WoT) {
  const int y = blockIdx.y;
  if (y < 3) {
    const float* in = y == 0 ? qin : (y == 1 ? kin : vin);
    u16* out = y == 0 ? qo : (y == 1 ? ko : vo);
    const int n = 2 * SEQ * DM;
    for (int i = (blockIdx.x * 256 + threadIdx.x) * 4; i < n; i += gridDim.x * 256 * 4) {
      float4 f = *(const float4*)(in + i);
      uint2 o;
      o.x = pack2(f.x, f.y);
      o.y = pack2(f.z, f.w);
      *(uint2*)(out + i) = o;
    }
  } else {
    const int z = y - 3;
    const float* W = z == 0 ? Wq : (z == 1 ? Wk : (z == 2 ? Wv : Wo));
    u16* Wt = z == 0 ? WqT : (z == 1 ? WkT : (z == 2 ? WvT : WoT));
    const int N = (z == 1 || z == 2) ? 256 : 1024;
    const int nt = blockIdx.x & 31, kt = blockIdx.x >> 5;
    const int n0 = nt * 32;
    if (n0 >= N) return;
    const int k0 = kt * 32;
    __shared__ float tile[32][33];
    int x = threadIdx.x & 31, yy = threadIdx.x >> 5;
#pragma unroll
    for (int i = 0; i < 4; i++)
      tile[yy + i * 8][x] = W[(size_t)(k0 + yy + i * 8) * N + n0 + x];
    __syncthreads();
#pragma unroll
    for (int i = 0; i < 4; i++)
      Wt[(size_t)(n0 + yy + i * 8) * 1024 + k0 + x] = f2bf(tile[x][yy + i * 8]);
  }
}

// ---------- shared 128x128 bf16 GEMM core: acc = A[M,K] * Bt[N,K]^T ----------
__device__ __forceinline__ void gemm_core(const u16* __restrict__ A, const u16* __restrict__ Bt,
                                          int m0, int n0, int K, u16* lA, u16* lB,
                                          f32x4 acc[4][4]) {
  const int tid = threadIdx.x;
  const int lane = tid & 63, wave = tid >> 6;
  const int l15 = lane & 15, quad = lane >> 4;
  const int wm = wave >> 1, wn = wave & 1;
  const int sr = tid >> 3, scol = (tid & 7) * 8;
  f32x4 zero = {0.f, 0.f, 0.f, 0.f};
#pragma unroll
  for (int i = 0; i < 4; i++)
#pragma unroll
    for (int j = 0; j < 4; j++) acc[i][j] = zero;

  for (int k0 = 0; k0 < K; k0 += 64) {
#pragma unroll
    for (int rr = 0; rr < 4; rr++) {
      int r = sr + rr * 32;
      *(uint4*)&lA[r * 72 + scol] = *(const uint4*)(A + (size_t)(m0 + r) * K + k0 + scol);
      *(uint4*)&lB[r * 72 + scol] = *(const uint4*)(Bt + (size_t)(n0 + r) * K + k0 + scol);
    }
    __syncthreads();
    short8 af[4][2], bfr[4][2];
#pragma unroll
    for (int i = 0; i < 4; i++)
#pragma unroll
      for (int kb = 0; kb < 2; kb++) {
        af[i][kb] = *(const short8*)&lA[(wm * 64 + i * 16 + l15) * 72 + kb * 32 + quad * 8];
        bfr[i][kb] = *(const short8*)&lB[(wn * 64 + i * 16 + l15) * 72 + kb * 32 + quad * 8];
      }
#pragma unroll
    for (int i = 0; i < 4; i++)
#pragma unroll
      for (int j = 0; j < 4; j++) {
        acc[i][j] = MFMA16(af[i][0], bfr[j][0], acc[i][j]);
        acc[i][j] = MFMA16(af[i][1], bfr[j][1], acc[i][j]);
      }
    __syncthreads();
  }
}

// ---------- fused Q/K/V projection GEMM ----------
// grid (32, 12). y<8: Q (operand-swapped -> vectorized stores); y in {8,9}: K (swapped);
// y in {10,11}: V (normal orientation; r-quad = 4 consecutive s -> packed V^T store).
__global__ __launch_bounds__(256) void k_proj(
    const u16* __restrict__ qa, const u16* __restrict__ ka, const u16* __restrict__ va,
    const u16* __restrict__ WqT, const u16* __restrict__ WkT, const u16* __restrict__ WvT,
    const float* __restrict__ bq, const float* __restrict__ bk, const float* __restrict__ bv,
    u16* __restrict__ qbf, float* __restrict__ outK, u16* __restrict__ kbf,
    float* __restrict__ outV, u16* __restrict__ vtb, float qscale) {
  __shared__ u16 lA[128 * 72];
  __shared__ u16 lB[128 * 72];
  const int by = blockIdx.y;
  const int lane = threadIdx.x & 63, wave = threadIdx.x >> 6;
  const int l15 = lane & 15, quad = lane >> 4;
  const int wm = wave >> 1, wn = wave & 1;
  f32x4 acc[4][4];

  if (by < 10) {
    // swapped: A = W^T (rows = output cols), Bt = activation (rows = tokens)
    const u16* Wt;
    const u16* act;
    const float* bias;
    int m0w, mode;
    if (by < 8) { Wt = WqT; act = qa; bias = bq; m0w = by * 128; mode = 0; }
    else { Wt = WkT; act = ka; bias = bk; m0w = (by - 8) * 128; mode = 1; }
    gemm_core(Wt, act, m0w, blockIdx.x * 128, 1024, lA, lB, acc);
#pragma unroll
    for (int i = 0; i < 4; i++) {
      int nb_ = m0w + wm * 64 + i * 16 + quad * 4;  // 4-aligned output col
      float4 bb = *(const float4*)(bias + nb_);
#pragma unroll
      for (int j = 0; j < 4; j++) {
        int srow = blockIdx.x * 128 + wn * 64 + j * 16 + l15;
        int b = srow >> 11, s = srow & 2047;
        float v0 = acc[i][j][0] + bb.x, v1 = acc[i][j][1] + bb.y;
        float v2 = acc[i][j][2] + bb.z, v3 = acc[i][j][3] + bb.w;
        if (mode == 0) {
          int h = nb_ >> 6, d = nb_ & 63;
          uint2 o;
          o.x = pack2(v0 * qscale, v1 * qscale);
          o.y = pack2(v2 * qscale, v3 * qscale);
          *(uint2*)(qbf + (((size_t)(b * 16 + h) * SEQ + s) << 6) + d) = o;
        } else {
          int kvh = nb_ >> 6, d = nb_ & 63;
          size_t idx = (((size_t)(b * 4 + kvh) * SEQ + s) << 6) + d;
          float4 vv = {v0, v1, v2, v3};
          *(float4*)(outK + idx) = vv;
          uint2 o;
          o.x = pack2(v0, v1);
          o.y = pack2(v2, v3);
          *(uint2*)(kbf + idx) = o;
        }
      }
    }
  } else {
    // V: normal orientation (rows = tokens). r-quad gives 4 consecutive s.
    const int n0v = (by - 10) * 128;
    gemm_core(va, WvT, blockIdx.x * 128, n0v, 1024, lA, lB, acc);
#pragma unroll
    for (int i = 0; i < 4; i++) {
      int rowg = blockIdx.x * 128 + wm * 64 + i * 16 + quad * 4;
      int b = rowg >> 11, s0 = rowg & 2047;
#pragma unroll
      for (int j = 0; j < 4; j++) {
        int colg = n0v + wn * 64 + j * 16 + l15;
        int kvh = colg >> 6, d = colg & 63;
        float bv_ = bv[colg];
        float v0 = acc[i][j][0] + bv_, v1 = acc[i][j][1] + bv_;
        float v2 = acc[i][j][2] + bv_, v3 = acc[i][j][3] + bv_;
        size_t base = (((size_t)(b * 4 + kvh) * SEQ + s0) << 6) + d;
        outV[base] = v0;
        outV[base + 64] = v1;
        outV[base + 128] = v2;
        outV[base + 192] = v3;
        uint2 o;
        o.x = pack2(v0, v1);
        o.y = pack2(v2, v3);
        *(uint2*)(vtb + ((size_t)(b * 4 + kvh) * 64 + d) * SEQ + s0) = o;
      }
    }
  }
}

// ---------- output projection GEMM (operand-swapped -> float4 stores) ----------
__global__ __launch_bounds__(256) void k_out(const u16* __restrict__ ctxb,
                                             const u16* __restrict__ WoT,
                                             const float* __restrict__ bo,
                                             float* __restrict__ out) {
  __shared__ u16 lA[128 * 72];
  __shared__ u16 lB[128 * 72];
  const int lane = threadIdx.x & 63, wave = threadIdx.x >> 6;
  const int l15 = lane & 15, quad = lane >> 4;
  const int wm = wave >> 1, wn = wave & 1;
  f32x4 acc[4][4];
  gemm_core(WoT, ctxb, blockIdx.y * 128, blockIdx.x * 128, 1024, lA, lB, acc);
#pragma unroll
  for (int i = 0; i < 4; i++) {
    int nb_ = blockIdx.y * 128 + wm * 64 + i * 16 + quad * 4;
    float4 bb = *(const float4*)(bo + nb_);
#pragma unroll
    for (int j = 0; j < 4; j++) {
      int srow = blockIdx.x * 128 + wn * 64 + j * 16 + l15;
      float4 vv = {acc[i][j][0] + bb.x, acc[i][j][1] + bb.y, acc[i][j][2] + bb.z,
                   acc[i][j][3] + bb.w};
      *(float4*)(out + (size_t)srow * DM + nb_) = vv;
    }
  }
}

// ---------- flash attention, 2-way key split (no-max softmax => additive partials) ----------
// grid (S/128, B*H, 2); 4 waves x 32 q-rows; 64-key tiles; each z handles 1024 keys.
// Writes unnormalized fp32 O^T partial [z][bh][q][d] + l [z][bh][q].
__global__ __launch_bounds__(256) void k_flash(
    const u16* __restrict__ Qh, const u16* __restrict__ Kb,
    const u16* __restrict__ Vt, float* __restrict__ Opart, float* __restrict__ lpart) {
  __shared__ u16 lK[64 * 72];
  __shared__ u16 lV[64 * 72];
  __shared__ u16 lP[4 * 32 * 72];
  const int tid = threadIdx.x;
  const int lane = tid & 63, wave = tid >> 6;
  const int l15 = lane & 15, quad = lane >> 4;
  const int bh = blockIdx.y, z = blockIdx.z;
  const int b = bh >> 4, h = bh & 15, kvh = h >> 2;
  const u16* Q = Qh + (size_t)bh * SEQ * 64;
  const u16* Kp = Kb + (size_t)(b * 4 + kvh) * SEQ * 64;
  const u16* Vp = Vt + (size_t)(b * 4 + kvh) * 64 * SEQ;
  const int q0 = blockIdx.x * 128 + wave * 32;
  const int kbase = z * 1024;

  // Q fragments in registers all pass (B-operand: n=l15, k=quad*8+j)
  short8 qf[2][2];
#pragma unroll
  for (int mb = 0; mb < 2; mb++)
#pragma unroll
    for (int kb = 0; kb < 2; kb++)
      qf[mb][kb] = *(const short8*)(Q + (size_t)(q0 + mb * 16 + l15) * 64 + kb * 32 + quad * 8);

  // ones A-fragment: row m=0 of A = 1.0 -> D row0 = column sums of B (= l per query)
  short8 ones8;
  {
    short ov = (l15 == 0) ? (short)0x3F80 : (short)0;
    ones8 = (short8){ov, ov, ov, ov, ov, ov, ov, ov};
  }

  f32x4 zero = {0.f, 0.f, 0.f, 0.f};
  f32x4 acc[2][4];  // O^T: row=d_local, col=q=l15
  f32x4 lacc[2];    // row0 @ quad0 holds l(q)
#pragma unroll
  for (int mb = 0; mb < 2; mb++) {
#pragma unroll
    for (int nb = 0; nb < 4; nb++) acc[mb][nb] = zero;
    lacc[mb] = zero;
  }

  const int sr = tid >> 3, scol = (tid & 7) * 8;  // 256 threads stage 64 rows in 2 passes
  u16* lPw = lP + wave * (32 * 72);

  uint4 pk[2], pv[2];
#pragma unroll
  for (int i = 0; i < 2; i++) {
    int r = sr + i * 32;
    pk[i] = *(const uint4*)(Kp + (size_t)(kbase + r) * 64 + scol);
    pv[i] = *(const uint4*)(Vp + (size_t)r * SEQ + kbase + scol);
  }

  for (int k0 = 0; k0 < 1024; k0 += 64) {
#pragma unroll
    for (int i = 0; i < 2; i++) {
      int r = sr + i * 32;
      *(uint4*)&lK[r * 72 + scol] = pk[i];
      *(uint4*)&lV[r * 72 + scol] = pv[i];
    }
    __syncthreads();
    if (k0 + 64 < 1024) {  // prefetch next tile while computing this one
      int kn = kbase + k0 + 64;
#pragma unroll
      for (int i = 0; i < 2; i++) {
        int r = sr + i * 32;
        pk[i] = *(const uint4*)(Kp + (size_t)(kn + r) * 64 + scol);
        pv[i] = *(const uint4*)(Vp + (size_t)r * SEQ + kn + scol);
      }
    }

    // S^T tiles: rows = keys, cols = q(l15). Scores already in log2 domain (qscale).
    f32x4 sc[2][4];
#pragma unroll
    for (int nb = 0; nb < 4; nb++) {
      short8 kf0 = *(const short8*)&lK[(nb * 16 + l15) * 72 + quad * 8];
      short8 kf1 = *(const short8*)&lK[(nb * 16 + l15) * 72 + 32 + quad * 8];
#pragma unroll
      for (int mb = 0; mb < 2; mb++) {
        f32x4 t = zero;
        t = MFMA16(kf0, qf[mb][0], t);
        t = MFMA16(kf1, qf[mb][1], t);
        sc[mb][nb] = t;
      }
    }

    // exp2 + truncating pack -> P in LDS [q][key]
#pragma unroll
    for (int mb = 0; mb < 2; mb++)
#pragma unroll
      for (int nb = 0; nb < 4; nb++) {
        float e0 = __builtin_amdgcn_exp2f(sc[mb][nb][0]);
        float e1 = __builtin_amdgcn_exp2f(sc[mb][nb][1]);
        float e2 = __builtin_amdgcn_exp2f(sc[mb][nb][2]);
        float e3 = __builtin_amdgcn_exp2f(sc[mb][nb][3]);
        uint2 p;
        p.x = pack2t(e0, e1);
        p.y = pack2t(e2, e3);
        *(uint2*)&lPw[(mb * 16 + l15) * 72 + nb * 16 + quad * 4] = p;
      }
    __asm__ volatile("s_waitcnt lgkmcnt(0)" ::: "memory");  // wave-local LDS handoff

    // O^T += V^T P^T ; l += ones * P^T
#pragma unroll
    for (int kb = 0; kb < 2; kb++) {
      short8 vfr[4];
#pragma unroll
      for (int nb = 0; nb < 4; nb++)
        vfr[nb] = *(const short8*)&lV[(nb * 16 + l15) * 72 + kb * 32 + quad * 8];
#pragma unroll
      for (int mb = 0; mb < 2; mb++) {
        short8 pf = *(const short8*)&lPw[(mb * 16 + l15) * 72 + kb * 32 + quad * 8];
        lacc[mb] = MFMA16(ones8, pf, lacc[mb]);
#pragma unroll
        for (int nb = 0; nb < 4; nb++) acc[mb][nb] = MFMA16(vfr[nb], pf, acc[mb][nb]);
      }
    }
    __syncthreads();
  }

  // epilogue: unnormalized partials. lane q = q0+mb*16+l15, d = nb*16+quad*4+{0..3}
  const size_t obase = ((size_t)(z * 32 + bh) * SEQ) * 64;
#pragma unroll
  for (int mb = 0; mb < 2; mb++) {
    int q = q0 + mb * 16 + l15;
    if (quad == 0) lpart[(size_t)(z * 32 + bh) * SEQ + q] = lacc[mb][0];
#pragma unroll
    for (int nb = 0; nb < 4; nb++)
      *(f32x4*)&Opart[obase + (size_t)q * 64 + nb * 16 + quad * 4] = acc[mb][nb];
  }
}

// ---------- combine partials -> ctx bf16 [B,S,DM] ----------
// grid 4096 x 256: idx -> (bh, q, d4)
__global__ void k_combine(const float* __restrict__ Opart, const float* __restrict__ lpart,
                          u16* __restrict__ ctx) {
  const int idx = blockIdx.x * 256 + threadIdx.x;
  const int d4 = idx & 15, q = (idx >> 4) & 2047, bh = idx >> 15;
  const size_t base = ((size_t)bh * SEQ + q) * 64 + d4 * 4;
  float4 o1 = *(const float4*)(Opart + base);
  float4 o2 = *(const float4*)(Opart + base + (size_t)32 * SEQ * 64);
  float l = lpart[(size_t)bh * SEQ + q] + lpart[(size_t)32 * SEQ + bh * SEQ + q];
  float inv = __builtin_amdgcn_rcpf(l);
  const int b = bh >> 4, h = bh & 15;
  uint2 o;
  o.x = pack2t((o1.x + o2.x) * inv, (o1.y + o2.y) * inv);
  o.y = pack2t((o1.z + o2.z) * inv, (o1.w + o2.w) * inv);
  *(uint2*)(ctx + ((size_t)(b * SEQ + q)) * DM + h * 64 + d4 * 4) = o;
}

extern "C" void kernel_launch(void* const* d_in, const int* in_sizes, int n_in,
                              void* d_out, int out_size, void* d_ws, size_t ws_size,
                              hipStream_t stream) {
  const float* query = (const float*)d_in[0];
  const float* key_in = (const float*)d_in[1];
  const float* value_in = (const float*)d_in[2];
  const float* Wq = (const float*)d_in[3];
  const float* bq = (const float*)d_in[4];
  const float* Wk = (const float*)d_in[5];
  const float* bk = (const float*)d_in[6];
  const float* Wv = (const float*)d_in[7];
  const float* bv = (const float*)d_in[8];
  const float* Wo = (const float*)d_in[9];
  const float* bo = (const float*)d_in[10];

  float* out = (float*)d_out;   // [B,S,DM]
  float* outK = out + 4194304;  // [B,KVH,S,64]
  float* outV = out + 5242880;  // [B,KVH,S,64]

  // Workspace overlay (lifetimes: prep/proj phase vs flash/combine phase):
  //  [0, 33.5M): q_act/k_act/v_act/WqT/WkT/WvT  -> after proj: Opart fp32 [2][32][2048][64]
  //  qbf (read by flash) -> after flash: ctxb (written by combine, read by k_out)
  char* ws = (char*)d_ws;
  u16* q_act = (u16*)(ws);                    // 8M
  u16* k_act = (u16*)(ws + 8388608);          // 8M
  u16* v_act = (u16*)(ws + 16777216);         // 8M
  u16* WqT = (u16*)(ws + 25165824);           // 2M
  u16* WkT = (u16*)(ws + 27262976);           // 0.5M
  u16* WvT = (u16*)(ws + 27787264);           // 0.5M
  float* Opart = (float*)(ws);                // 32M (overlays the six above, post-proj)
  float* lpart = (float*)(ws + 33554432);     // 0.5M
  u16* WoT = (u16*)(ws + 34078720);           // 2M (must survive until k_out)
  u16* qbf = (u16*)(ws + 36175872);           // 8M  Q bf16 [B,H,S,64], pre-scaled log2e/8
  u16* ctxb = (u16*)(ws + 36175872);          // 8M  (overlays qbf, post-flash)
  u16* kbf = (u16*)(ws + 44564480);           // 2M  K bf16 [B,KVH,S,64]
  u16* vtb = (u16*)(ws + 46661632);           // 2M  V^T bf16 [B,KVH,64,S]
  // high-water: 48,758,784 bytes

  const float qscale = 0.125f * 1.44269504088896340736f;  // fold log2(e) -> exp2 softmax

  k_prep<<<dim3(1024, 7), 256, 0, stream>>>(query, key_in, value_in, Wq, Wk, Wv, Wo, q_act,
                                            k_act, v_act, WqT, WkT, WvT, WoT);
  k_proj<<<dim3(32, 12), 256, 0, stream>>>(q_act, k_act, v_act, WqT, WkT, WvT, bq, bk, bv,
                                           qbf, outK, kbf, outV, vtb, qscale);
  k_flash<<<dim3(16, 32, 2), 256, 0, stream>>>(qbf, kbf, vtb, Opart, lpart);
  k_combine<<<dim3(4096), 256, 0, stream>>>(Opart, lpart, ctxb);
  k_out<<<dim3(32, 8), 256, 0, stream>>>(ctxb, WoT, bo, out);
}

// Round 5
// 212.131 us; speedup vs baseline: 1.2951x; 1.2951x over previous
//
#include <hip/hip_runtime.h>

typedef unsigned short u16;
typedef unsigned int u32;
typedef __attribute__((ext_vector_type(8))) short short8;
typedef __attribute__((ext_vector_type(4))) float f32x4;

#define MFMA16(a, b, c) __builtin_amdgcn_mfma_f32_16x16x32_bf16(a, b, c, 0, 0, 0)

// B=2, S=2048, D=1024, H=16, KVH=4, dk=64, G=4
#define SEQ 2048
#define DM 1024

__device__ __forceinline__ u16 f2bf(float f) {
  u32 u = __float_as_uint(f);
  u += 0x7fffu + ((u >> 16) & 1u);  // RNE
  return (u16)(u >> 16);
}
__device__ __forceinline__ u32 pack2(float a, float b) {  // RNE pack
  return (u32)f2bf(a) | ((u32)f2bf(b) << 16);
}
__device__ __forceinline__ u32 pack2t(float a, float b) {  // truncating pack: 1 v_perm
  return __builtin_amdgcn_perm(__float_as_uint(b), __float_as_uint(a), 0x07060302u);
}

// load 8 contiguous elems as bf16x8 (uint4); F32 -> convert on the fly (fused k_prep)
template <bool F32>
__device__ __forceinline__ uint4 ld8(const void* p, size_t elem) {
  if constexpr (F32) {
    const float* f = (const float*)p + elem;
    float4 a = *(const float4*)f;
    float4 b = *(const float4*)(f + 4);
    uint4 r;
    r.x = pack2(a.x, a.y);
    r.y = pack2(a.z, a.w);
    r.z = pack2(b.x, b.y);
    r.w = pack2(b.z, b.w);
    return r;
  } else {
    return *(const uint4*)((const u16*)p + elem);
  }
}

// ---------- weight transposes W[K,N] fp32 -> Wt[N,K] bf16 ----------
__global__ void k_tr(const float* __restrict__ Wq, const float* __restrict__ Wk,
                     const float* __restrict__ Wv, const float* __restrict__ Wo,
                     u16* __restrict__ WqT, u16* __restrict__ WkT, u16* __restrict__ WvT,
                     u16* __restrict__ WoT) {
  const int z = blockIdx.z;
  const float* W = z == 0 ? Wq : (z == 1 ? Wk : (z == 2 ? Wv : Wo));
  u16* Wt = z == 0 ? WqT : (z == 1 ? WkT : (z == 2 ? WvT : WoT));
  const int N = (z == 1 || z == 2) ? 256 : 1024;
  const int n0 = blockIdx.x * 32;
  if (n0 >= N) return;
  const int k0 = blockIdx.y * 32;
  __shared__ float tile[32][33];
  int x = threadIdx.x & 31, y = threadIdx.x >> 5;
#pragma unroll
  for (int i = 0; i < 4; i++)
    tile[y + i * 8][x] = W[(size_t)(k0 + y + i * 8) * N + n0 + x];
  __syncthreads();
#pragma unroll
  for (int i = 0; i < 4; i++)
    Wt[(size_t)(n0 + y + i * 8) * 1024 + k0 + x] = f2bf(tile[x][y + i * 8]);
}

// ---------- 64x128 bf16 GEMM core: acc = A[64-tile,K] * Bt[128-tile,K]^T, K=1024 ----------
// waves: wm=wave>>1 picks 32-row half (2 mtiles of 16), wn=wave&1 picks 64-col half (4 ntiles)
template <bool A32, bool B32>
__device__ __forceinline__ void gemm64(const void* __restrict__ A, const void* __restrict__ Bt,
                                       int m0, int n0, u16* lA, u16* lB, f32x4 acc[2][4]) {
  const int tid = threadIdx.x;
  const int lane = tid & 63, wave = tid >> 6;
  const int l15 = lane & 15, quad = lane >> 4;
  const int wm = wave >> 1, wn = wave & 1;
  const int sr = tid >> 3, scol = (tid & 7) * 8;
  f32x4 zero = {0.f, 0.f, 0.f, 0.f};
#pragma unroll
  for (int i = 0; i < 2; i++)
#pragma unroll
    for (int j = 0; j < 4; j++) acc[i][j] = zero;

  for (int k0 = 0; k0 < 1024; k0 += 64) {
#pragma unroll
    for (int it = 0; it < 2; it++) {
      int r = sr + it * 32;
      *(uint4*)&lA[r * 72 + scol] = ld8<A32>(A, (size_t)(m0 + r) * 1024 + k0 + scol);
    }
#pragma unroll
    for (int it = 0; it < 4; it++) {
      int r = sr + it * 32;
      *(uint4*)&lB[r * 72 + scol] = ld8<B32>(Bt, (size_t)(n0 + r) * 1024 + k0 + scol);
    }
    __syncthreads();
    short8 af[2][2], bfr[4][2];
#pragma unroll
    for (int i = 0; i < 2; i++)
#pragma unroll
      for (int kb = 0; kb < 2; kb++)
        af[i][kb] = *(const short8*)&lA[(wm * 32 + i * 16 + l15) * 72 + kb * 32 + quad * 8];
#pragma unroll
    for (int j = 0; j < 4; j++)
#pragma unroll
      for (int kb = 0; kb < 2; kb++)
        bfr[j][kb] = *(const short8*)&lB[(wn * 64 + j * 16 + l15) * 72 + kb * 32 + quad * 8];
#pragma unroll
    for (int i = 0; i < 2; i++)
#pragma unroll
      for (int j = 0; j < 4; j++) {
        acc[i][j] = MFMA16(af[i][0], bfr[j][0], acc[i][j]);
        acc[i][j] = MFMA16(af[i][1], bfr[j][1], acc[i][j]);
      }
    __syncthreads();
  }
}

// ---------- fused Q/K/V projection (conversion fused into staging) ----------
// flat grid 768: [0,512) Q (swapped: A=WqT 16 mtiles, B=query 32 ntiles)
//                [512,640) K (A=WkT 4 mtiles, B=key_in 32 ntiles)
//                [640,768) V (A=value_in 64 mtiles, B=WvT 2 ntiles)
__global__ __launch_bounds__(256) void k_proj(
    const float* __restrict__ query, const float* __restrict__ key_in,
    const float* __restrict__ value_in, const u16* __restrict__ WqT,
    const u16* __restrict__ WkT, const u16* __restrict__ WvT, const float* __restrict__ bq,
    const float* __restrict__ bk, const float* __restrict__ bv, u16* __restrict__ qbf,
    float* __restrict__ outK, u16* __restrict__ kbf, float* __restrict__ outV,
    u16* __restrict__ vtb, float qscale) {
  __shared__ u16 lA[64 * 72];
  __shared__ u16 lB[128 * 72];
  const int idx = blockIdx.x;
  const int lane = threadIdx.x & 63, wave = threadIdx.x >> 6;
  const int l15 = lane & 15, quad = lane >> 4;
  const int wm = wave >> 1, wn = wave & 1;
  f32x4 acc[2][4];

  if (idx < 640) {
    const u16* Wt;
    const float* act;
    const float* bias;
    int m0, n0, mode;
    if (idx < 512) {
      Wt = WqT; act = query; bias = bq; m0 = (idx >> 5) * 64; n0 = (idx & 31) * 128; mode = 0;
    } else {
      int i2 = idx - 512;
      Wt = WkT; act = key_in; bias = bk; m0 = (i2 >> 5) * 64; n0 = (i2 & 31) * 128; mode = 1;
    }
    gemm64<false, true>(Wt, act, m0, n0, lA, lB, acc);
#pragma unroll
    for (int i = 0; i < 2; i++) {
      int c0 = m0 + wm * 32 + i * 16 + quad * 4;  // output col, 4-aligned
      float4 bb = *(const float4*)(bias + c0);
#pragma unroll
      for (int j = 0; j < 4; j++) {
        int token = n0 + wn * 64 + j * 16 + l15;
        int b = token >> 11, s = token & 2047;
        float v0 = acc[i][j][0] + bb.x, v1 = acc[i][j][1] + bb.y;
        float v2 = acc[i][j][2] + bb.z, v3 = acc[i][j][3] + bb.w;
        int d = c0 & 63;
        if (mode == 0) {
          int h = c0 >> 6;
          uint2 o;
          o.x = pack2(v0 * qscale, v1 * qscale);
          o.y = pack2(v2 * qscale, v3 * qscale);
          *(uint2*)(qbf + (((size_t)(b * 16 + h) * SEQ + s) << 6) + d) = o;
        } else {
          int kvh = c0 >> 6;
          size_t ix = (((size_t)(b * 4 + kvh) * SEQ + s) << 6) + d;
          float4 vv = {v0, v1, v2, v3};
          *(float4*)(outK + ix) = vv;
          uint2 o;
          o.x = pack2(v0, v1);
          o.y = pack2(v2, v3);
          *(uint2*)(kbf + ix) = o;
        }
      }
    }
  } else {
    int i2 = idx - 640;
    int m0 = (i2 >> 1) * 64, n0 = (i2 & 1) * 128;
    gemm64<true, false>(value_in, WvT, m0, n0, lA, lB, acc);
#pragma unroll
    for (int i = 0; i < 2; i++) {
      int r0 = m0 + wm * 32 + i * 16 + quad * 4;  // token, 4-aligned
      int b = r0 >> 11, s0 = r0 & 2047;
#pragma unroll
      for (int j = 0; j < 4; j++) {
        int col = n0 + wn * 64 + j * 16 + l15;
        int kvh = col >> 6, d = col & 63;
        float bv_ = bv[col];
        float v0 = acc[i][j][0] + bv_, v1 = acc[i][j][1] + bv_;
        float v2 = acc[i][j][2] + bv_, v3 = acc[i][j][3] + bv_;
        size_t base = (((size_t)(b * 4 + kvh) * SEQ + s0) << 6) + d;
        outV[base] = v0;
        outV[base + 64] = v1;
        outV[base + 128] = v2;
        outV[base + 192] = v3;
        uint2 o;
        o.x = pack2(v0, v1);
        o.y = pack2(v2, v3);
        *(uint2*)(vtb + ((size_t)(b * 4 + kvh) * 64 + d) * SEQ + s0) = o;  // V^T
      }
    }
  }
}

// ---------- output projection (swapped: A=WoT 16 mtiles, B=ctxb 32 ntiles) ----------
__global__ __launch_bounds__(256) void k_out(const u16* __restrict__ ctxb,
                                             const u16* __restrict__ WoT,
                                             const float* __restrict__ bo,
                                             float* __restrict__ out) {
  __shared__ u16 lA[64 * 72];
  __shared__ u16 lB[128 * 72];
  const int idx = blockIdx.x;
  const int m0 = (idx >> 5) * 64, n0 = (idx & 31) * 128;
  const int lane = threadIdx.x & 63, wave = threadIdx.x >> 6;
  const int l15 = lane & 15, quad = lane >> 4;
  const int wm = wave >> 1, wn = wave & 1;
  f32x4 acc[2][4];
  gemm64<false, false>(WoT, ctxb, m0, n0, lA, lB, acc);
#pragma unroll
  for (int i = 0; i < 2; i++) {
    int c0 = m0 + wm * 32 + i * 16 + quad * 4;
    float4 bb = *(const float4*)(bo + c0);
#pragma unroll
    for (int j = 0; j < 4; j++) {
      int token = n0 + wn * 64 + j * 16 + l15;
      float4 vv = {acc[i][j][0] + bb.x, acc[i][j][1] + bb.y, acc[i][j][2] + bb.z,
                   acc[i][j][3] + bb.w};
      *(float4*)(out + (size_t)token * DM + c0) = vv;
    }
  }
}

// ---------- flash attention: 128-key LDS segments, 2 barrier-free subtiles each ----------
// grid (S/64, B*H); 4 waves x 16 q. XOR-swizzled stride-64 LDS (40KB -> 4 blocks/CU).
// S^T = K.Q^T (softmax axis = C rows); no-max softmax (scores provably small);
// l via ones-row MFMA over the same truncated P.
__global__ __launch_bounds__(256, 4) void k_flash(const u16* __restrict__ Qh,
                                                  const u16* __restrict__ Kb,
                                                  const u16* __restrict__ Vt,
                                                  u16* __restrict__ ctx) {
  __shared__ u16 lK[128 * 64];    // [key][d], 8 chunks/row, chunk' = ch ^ (row&7)
  __shared__ u16 lV[64 * 128];    // [d][key], 16 chunks/row, chunk' = ch ^ (row&15)
  __shared__ u16 lP[4 * 16 * 64]; // per-wave [q][key(64)], 8 chunks, ch ^ (q&7)
  const int tid = threadIdx.x;
  const int lane = tid & 63, wave = tid >> 6;
  const int l15 = lane & 15, quad = lane >> 4;
  const int bh = blockIdx.y;
  const int b = bh >> 4, h = bh & 15, kvh = h >> 2;
  const u16* Q = Qh + (size_t)bh * SEQ * 64;
  const u16* Kp = Kb + (size_t)(b * 4 + kvh) * SEQ * 64;
  const u16* Vp = Vt + (size_t)(b * 4 + kvh) * 64 * SEQ;
  const int q0 = blockIdx.x * 64 + wave * 16;

  // Q B-operand fragments (n=q=l15, k=quad*8+j), resident all pass
  short8 qf[2];
#pragma unroll
  for (int kb = 0; kb < 2; kb++)
    qf[kb] = *(const short8*)(Q + (size_t)(q0 + l15) * 64 + kb * 32 + quad * 8);

  short8 ones8;
  {
    short ov = (l15 == 0) ? (short)0x3F80 : (short)0;
    ones8 = (short8){ov, ov, ov, ov, ov, ov, ov, ov};
  }

  f32x4 zero = {0.f, 0.f, 0.f, 0.f};
  f32x4 acc[4];  // O^T: acc[n] rows d=n*16+quad*4+r, col q=l15
  f32x4 lacc = zero;
#pragma unroll
  for (int n = 0; n < 4; n++) acc[n] = zero;

  u16* lPw = lP + wave * (16 * 64);
  const int t8 = tid * 8;

  for (int kc = 0; kc < SEQ; kc += 128) {
    __syncthreads();  // prior segment fully consumed
    // stage K 16KB: 4 coalesced 4KB slabs, swizzled LDS writes
#pragma unroll
    for (int i = 0; i < 4; i++) {
      int e = i * 2048 + t8;
      int row = e >> 6, ch = tid & 7;
      uint4 v = *(const uint4*)(Kp + (size_t)kc * 64 + e);
      *(uint4*)&lK[row * 64 + ((ch ^ (row & 7)) << 3)] = v;
    }
    // stage V^T 16KB
#pragma unroll
    for (int i = 0; i < 4; i++) {
      int e = i * 2048 + t8;
      int row = e >> 7, ch = tid & 15;
      uint4 v = *(const uint4*)(Vp + (size_t)row * SEQ + kc + ch * 8);
      *(uint4*)&lV[row * 128 + ((ch ^ (row & 15)) << 3)] = v;
    }
    __syncthreads();

#pragma unroll
    for (int sub = 0; sub < 2; sub++) {
      const int ks = sub * 64;
      // S^T = K.Q^T : 4 key-mtiles x 16 q
      f32x4 sc[4];
#pragma unroll
      for (int mt = 0; mt < 4; mt++) {
        int row = ks + mt * 16 + l15;
        short8 kf0 = *(const short8*)&lK[row * 64 + ((quad ^ (row & 7)) << 3)];
        short8 kf1 = *(const short8*)&lK[row * 64 + (((4 + quad) ^ (row & 7)) << 3)];
        f32x4 t = MFMA16(kf0, qf[0], zero);
        sc[mt] = MFMA16(kf1, qf[1], t);
      }
      // exp2 + truncate -> P[q][key] (wave-local LDS)
#pragma unroll
      for (int mt = 0; mt < 4; mt++) {
        float e0 = __builtin_amdgcn_exp2f(sc[mt][0]);
        float e1 = __builtin_amdgcn_exp2f(sc[mt][1]);
        float e2 = __builtin_amdgcn_exp2f(sc[mt][2]);
        float e3 = __builtin_amdgcn_exp2f(sc[mt][3]);
        int chp = mt * 2 + (quad >> 1);
        uint2 p;
        p.x = pack2t(e0, e1);
        p.y = pack2t(e2, e3);
        *(uint2*)&lPw[l15 * 64 + ((chp ^ (l15 & 7)) << 3) + (quad & 1) * 4] = p;
      }
      __asm__ volatile("s_waitcnt lgkmcnt(0)" ::: "memory");  // wave-local handoff
      // O^T += V^T.P^T ; l += ones.P^T
#pragma unroll
      for (int kbp = 0; kbp < 2; kbp++) {
        int chq = kbp * 4 + quad;
        short8 pf = *(const short8*)&lPw[l15 * 64 + ((chq ^ (l15 & 7)) << 3)];
        lacc = MFMA16(ones8, pf, lacc);
#pragma unroll
        for (int n = 0; n < 4; n++) {
          int row = n * 16 + l15;
          int chv = sub * 8 + kbp * 4 + quad;
          short8 vf = *(const short8*)&lV[row * 128 + ((chv ^ (row & 15)) << 3)];
          acc[n] = MFMA16(vf, pf, acc[n]);
        }
      }
    }
  }

  // epilogue: lane q = q0+l15, d = n*16+quad*4+{0..3}
  float lq = __shfl(lacc[0], l15);  // l(q) lives at quad0 reg0, lane l15
  float inv = __builtin_amdgcn_rcpf(lq);
  u16* base = ctx + ((size_t)(b * SEQ + q0 + l15)) * DM + h * 64;
#pragma unroll
  for (int n = 0; n < 4; n++) {
    uint2 o;
    o.x = pack2t(acc[n][0] * inv, acc[n][1] * inv);
    o.y = pack2t(acc[n][2] * inv, acc[n][3] * inv);
    *(uint2*)(base + n * 16 + quad * 4) = o;
  }
}

extern "C" void kernel_launch(void* const* d_in, const int* in_sizes, int n_in,
                              void* d_out, int out_size, void* d_ws, size_t ws_size,
                              hipStream_t stream) {
  const float* query = (const float*)d_in[0];
  const float* key_in = (const float*)d_in[1];
  const float* value_in = (const float*)d_in[2];
  const float* Wq = (const float*)d_in[3];
  const float* bq = (const float*)d_in[4];
  const float* Wk = (const float*)d_in[5];
  const float* bk = (const float*)d_in[6];
  const float* Wv = (const float*)d_in[7];
  const float* bv = (const float*)d_in[8];
  const float* Wo = (const float*)d_in[9];
  const float* bo = (const float*)d_in[10];

  float* out = (float*)d_out;   // [B,S,DM]
  float* outK = out + 4194304;  // [B,KVH,S,64]
  float* outV = out + 5242880;  // [B,KVH,S,64]

  char* ws = (char*)d_ws;
  u16* WqT = (u16*)(ws);               // 2M   [1024,1024] bf16
  u16* WkT = (u16*)(ws + 2097152);     // 0.5M [256,1024]
  u16* WvT = (u16*)(ws + 2621440);     // 0.5M
  u16* WoT = (u16*)(ws + 3145728);     // 2M
  u16* qbf = (u16*)(ws + 5242880);     // 8M  Q bf16 [B,H,S,64], pre-scaled log2e/8
  u16* kbf = (u16*)(ws + 13631488);    // 2M  K bf16 [B,KVH,S,64]
  u16* vtb = (u16*)(ws + 15728640);    // 2M  V^T bf16 [B,KVH,64,S]
  u16* ctxb = (u16*)(ws + 17825792);   // 8M  ctx bf16 [B,S,DM]
  // high-water: 26,214,400 bytes

  const float qscale = 0.125f * 1.44269504088896340736f;  // fold log2(e) -> exp2 softmax

  k_tr<<<dim3(32, 32, 4), 256, 0, stream>>>(Wq, Wk, Wv, Wo, WqT, WkT, WvT, WoT);
  k_proj<<<dim3(768), 256, 0, stream>>>(query, key_in, value_in, WqT, WkT, WvT, bq, bk, bv,
                                        qbf, outK, kbf, outV, vtb, qscale);
  k_flash<<<dim3(32, 32), 256, 0, stream>>>(qbf, kbf, vtb, ctxb);
  k_out<<<dim3(512), 256, 0, stream>>>(ctxb, WoT, bo, out);
}